// Round 11
// baseline (26.131 us; speedup 1.0000x reference)
//
#include <hip/hip_runtime.h>
#include <math.h>

#define HALF 5
#define BLOCK 256
#define GRP 1024              // outputs per group per block (BLOCK*4)
#define TILE (2*GRP)          // 2048 outputs per block, two lane-consecutive groups

typedef float floatx4 __attribute__((ext_vector_type(4)));

__global__ __launch_bounds__(BLOCK) void dilation1d_kernel(
    const float* __restrict__ in, const float* __restrict__ scale_p,
    float* __restrict__ out, int N)
{
    const float inv4s = 1.0f / (4.0f * scale_p[0]);
    // h[d] = -(d^2)/(4*scale); symmetric; h[0] = -0.0 (exact identity add)
    float h[HALF + 1];
    #pragma unroll
    for (int d = 0; d <= HALF; ++d) h[d] = -(float)(d * d) * inv4s;

    const int t  = threadIdx.x;
    const int g0 = blockIdx.x * TILE;
    const bool interior = (blockIdx.x != 0) && (blockIdx.x != gridDim.x - 1);

    // Two independent groups per thread; every load/store lane-consecutive.
    float r[2][20];   // r[g][j] = in[gbase_g - 8 + j]
    int   gbase[2];
    #pragma unroll
    for (int g = 0; g < 2; ++g) {
        gbase[g] = g0 + g * GRP + t * 4;          // first output idx of group
        const int lb = gbase[g] - 8;              // 16B-aligned first load idx
        if (interior) {
            const floatx4* p = (const floatx4*)(in + lb);
            #pragma unroll
            for (int v = 0; v < 5; ++v) {
                floatx4 f = p[v];
                r[g][v*4+0] = f.x; r[g][v*4+1] = f.y;
                r[g][v*4+2] = f.z; r[g][v*4+3] = f.w;
            }
        } else {
            #pragma unroll
            for (int j = 0; j < 20; ++j) {
                int idx = lb + j;
                r[g][j] = ((unsigned)idx < (unsigned)N) ? in[idx] : -INFINITY;
            }
        }
    }

    // out[i] = max_d ( max(x[i-d], x[i+d]) + h[d] ), center tap free.
    // Bit-exact vs reference: RN monotone => max(a,b)+h == max(a+h,b+h).
    #pragma unroll
    for (int g = 0; g < 2; ++g) {
        float o[4];
        #pragma unroll
        for (int u = 0; u < 4; ++u) {
            float m = r[g][u + 8];
            #pragma unroll
            for (int d = 1; d <= HALF; ++d)
                m = fmaxf(m, fmaxf(r[g][u + 8 - d], r[g][u + 8 + d]) + h[d]);
            o[u] = m;
        }
        if (interior) {
            // Lane-consecutive 16B NT stores: full 128B lines, no amplification,
            // skips L2/L3 allocation for the never-re-read output stream.
            floatx4 w = {o[0], o[1], o[2], o[3]};
            __builtin_nontemporal_store(w, (floatx4*)(out + gbase[g]));
        } else {
            #pragma unroll
            for (int u = 0; u < 4; ++u)
                if (gbase[g] + u < N) out[gbase[g] + u] = o[u];
        }
    }
}

extern "C" void kernel_launch(void* const* d_in, const int* in_sizes, int n_in,
                              void* d_out, int out_size, void* d_ws, size_t ws_size,
                              hipStream_t stream) {
    const float* in      = (const float*)d_in[0];
    const float* scale_p = (const float*)d_in[1];
    float* out           = (float*)d_out;
    const int N = in_sizes[0];
    const int grid = (N + TILE - 1) / TILE;
    hipLaunchKernelGGL(dilation1d_kernel, dim3(grid), dim3(BLOCK), 0, stream,
                       in, scale_p, out, N);
}

// Round 12
// 25.965 us; speedup vs baseline: 1.0064x; 1.0064x over previous
//
#include <hip/hip_runtime.h>
#include <math.h>

#define HALF 5
#define BLOCK 256
#define EPT 4             // outputs per thread -> lane-consecutive float4 I/O
#define TILE (BLOCK*EPT)  // 1024 outputs per block

typedef float floatx4 __attribute__((ext_vector_type(4)));

__global__ __launch_bounds__(BLOCK) void dilation1d_kernel(
    const float* __restrict__ in, const float* __restrict__ scale_p,
    float* __restrict__ out, int N)
{
    const float inv4s = 1.0f / (4.0f * scale_p[0]);
    // h[d] = -(d^2)/(4*scale); symmetric; h[0] = -0.0 (exact identity add)
    float h[HALF + 1];
    #pragma unroll
    for (int d = 0; d <= HALF; ++d) h[d] = -(float)(d * d) * inv4s;

    const int t = threadIdx.x;
    const int base  = blockIdx.x * TILE + t * EPT; // first output index
    const int lbase = base - 8;                    // 16B-aligned first loaded idx

    // r[j] = in[base-8+j], j=0..19 ; windows need j = u+3 .. u+13, u<4
    // For fixed v, lanes read lbase + v*16B with lbase lane-consecutive:
    // each load instruction covers 1KB contiguous per wave -> fully coalesced.
    float r[20];
    const bool interior = (blockIdx.x != 0) && (blockIdx.x != gridDim.x - 1);
    if (interior) {
        const floatx4* p = (const floatx4*)(in + lbase);
        #pragma unroll
        for (int v = 0; v < 5; ++v) {
            floatx4 f = p[v];
            r[v*4+0] = f.x; r[v*4+1] = f.y; r[v*4+2] = f.z; r[v*4+3] = f.w;
        }
    } else {
        #pragma unroll
        for (int j = 0; j < 20; ++j) {
            int idx = lbase + j;
            r[j] = ((unsigned)idx < (unsigned)N) ? in[idx] : -INFINITY;
        }
    }

    // out[base+u] = max_d ( max(x[i-d], x[i+d]) + h[d] ), center tap free.
    // Bit-exact vs reference: RN monotone => max(a,b)+h == max(a+h,b+h).
    float o[EPT];
    #pragma unroll
    for (int u = 0; u < EPT; ++u) {
        float m = r[u + 8];
        #pragma unroll
        for (int d = 1; d <= HALF; ++d)
            m = fmaxf(m, fmaxf(r[u + 8 - d], r[u + 8 + d]) + h[d]);
        o[u] = m;
    }

    if (interior) {
        // Lane-consecutive 16B stores: each wave inst = 8 full 128B lines.
        // NT skips L2/L3 allocation for the never-re-read output stream;
        // full-line coverage means no partial-sector write amplification.
        floatx4 w = {o[0], o[1], o[2], o[3]};
        __builtin_nontemporal_store(w, (floatx4*)(out + base));
    } else {
        #pragma unroll
        for (int u = 0; u < EPT; ++u)
            if (base + u < N) out[base + u] = o[u];
    }
}

extern "C" void kernel_launch(void* const* d_in, const int* in_sizes, int n_in,
                              void* d_out, int out_size, void* d_ws, size_t ws_size,
                              hipStream_t stream) {
    const float* in      = (const float*)d_in[0];
    const float* scale_p = (const float*)d_in[1];
    float* out           = (float*)d_out;
    const int N = in_sizes[0];
    const int grid = (N + TILE - 1) / TILE;
    hipLaunchKernelGGL(dilation1d_kernel, dim3(grid), dim3(BLOCK), 0, stream,
                       in, scale_p, out, N);
}